// Round 19
// baseline (705.716 us; speedup 1.0000x reference)
//
#include <hip/hip_runtime.h>

#define HEADS 4
#define EPS 1e-16f
#define NR 256    // dst ranges (counting-sort buckets)
#define EPB 2048  // edges per scatter block

typedef float floatx2 __attribute__((ext_vector_type(2)));
typedef short bf16x8 __attribute__((ext_vector_type(8)));
typedef float f32x4 __attribute__((ext_vector_type(4)));

// bf16 RNE pack
__device__ inline unsigned short f2bf(float f) {
    union { float f; unsigned u; } v; v.f = f;
    unsigned r = v.u + 0x7FFFu + ((v.u >> 16) & 1u);
    return (unsigned short)(r >> 16);
}
__device__ inline unsigned char f2fp8(float f) {
    return (unsigned char)(__builtin_amdgcn_cvt_pk_fp8_f32(f, 0.f, 0u, false) & 0xFF);
}

// exact dst-range classifier: q = dst / rdiv (float approx + integer fix)
__device__ inline int rangeOf(int dst, int rdiv, float rinv) {
    int q = (int)((float)dst * rinv);
    if (q > NR - 1) q = NR - 1;
    if ((long long)q * rdiv > dst) --q;
    else if ((long long)(q + 1) * rdiv <= dst) ++q;
    return q;
}

// ==== CSR 1: per-(block,range) counts. LDS atomics only ===================
__global__ __launch_bounds__(256) void scatter_count(
    const int* __restrict__ ei, int E, int rdiv, float rinv,
    int* __restrict__ pcnt)
{
    __shared__ int cnt[NR];
    int b = blockIdx.x, t = threadIdx.x;
    int b0 = b * EPB;
    int nloc = min(EPB, E - b0);
    cnt[t] = 0;
    __syncthreads();
    #pragma unroll
    for (int u = 0; u < 8; ++u) {
        int li = u * 256 + t;
        if (li < nloc)
            atomicAdd(&cnt[rangeOf(ei[E + b0 + li], rdiv, rinv)], 1);
    }
    __syncthreads();
    pcnt[(size_t)b * NR + t] = cnt[t];
}

// ==== CSR 2: per-range prefix over blocks (pcnt -> within-range offsets) ==
__global__ __launch_bounds__(256) void qprefix(
    int* __restrict__ pcnt, int nb, int* __restrict__ qtot)
{
    __shared__ int part[256];
    int q = blockIdx.x, t = threadIdx.x;
    int per = (nb + 255) >> 8;
    int lo = t * per, hi = min(lo + per, nb);
    int s = 0;
    for (int b = lo; b < hi; ++b) s += pcnt[(size_t)b * NR + q];
    part[t] = s;
    __syncthreads();
    for (int off = 1; off < 256; off <<= 1) {
        int a = (t >= off) ? part[t - off] : 0;
        __syncthreads();
        part[t] += a;
        __syncthreads();
    }
    if (t == 255) qtot[q] = part[255];
    int pre = (t == 0) ? 0 : part[t - 1];
    for (int b = lo; b < hi; ++b) {
        int c = pcnt[(size_t)b * NR + q];
        pcnt[(size_t)b * NR + q] = pre;
        pre += c;
    }
}

// ==== CSR 3: scan 256 range totals -> rstart[NR+1] ========================
__global__ void qscan(const int* __restrict__ qtot, int* __restrict__ rstart)
{
    __shared__ int tmp[NR];
    int t = threadIdx.x;
    tmp[t] = qtot[t];
    __syncthreads();
    for (int off = 1; off < NR; off <<= 1) {
        int a = (t >= off) ? tmp[t - off] : 0;
        __syncthreads();
        tmp[t] += a;
        __syncthreads();
    }
    rstart[t] = (t == 0) ? 0 : tmp[t - 1];
    if (t == NR - 1) rstart[NR] = tmp[NR - 1];
}

// ==== CSR 4: place edges into range-grouped SoA. No global atomics ========
__global__ __launch_bounds__(256) void scatter_place(
    const int* __restrict__ ei, int E, int rdiv, float rinv,
    const int* __restrict__ pcnt, const int* __restrict__ rstart,
    int* __restrict__ rsrc, int* __restrict__ rdst)
{
    __shared__ int2 lrec[EPB];
    __shared__ unsigned char lq[EPB];
    __shared__ int cnt[NR], base[NR], scn[NR];
    int b = blockIdx.x, t = threadIdx.x;
    int b0 = b * EPB;
    int nloc = min(EPB, E - b0);
    cnt[t] = 0;
    __syncthreads();
    int myq[8], myoff[8];
    int2 myrec[8];
    #pragma unroll
    for (int u = 0; u < 8; ++u) {
        int li = u * 256 + t;
        if (li < nloc) {
            int e = b0 + li;
            int sv = ei[e], dv = ei[E + e];
            int q = rangeOf(dv, rdiv, rinv);
            myq[u] = q;
            myrec[u] = make_int2(sv, dv);
            myoff[u] = atomicAdd(&cnt[q], 1);
        } else myq[u] = -1;
    }
    __syncthreads();
    scn[t] = cnt[t];
    __syncthreads();
    for (int off = 1; off < 256; off <<= 1) {
        int a = (t >= off) ? scn[t - off] : 0;
        __syncthreads();
        scn[t] += a;
        __syncthreads();
    }
    base[t] = (t == 0) ? 0 : scn[t - 1];
    __syncthreads();
    #pragma unroll
    for (int u = 0; u < 8; ++u) {
        if (myq[u] >= 0) {
            int slot = base[myq[u]] + myoff[u];
            lrec[slot] = myrec[u];
            lq[slot] = (unsigned char)myq[u];
        }
    }
    __syncthreads();
    #pragma unroll
    for (int u = 0; u < 8; ++u) {
        int s2 = u * 256 + t;
        if (s2 < nloc) {
            int q = lq[s2];
            int g = rstart[q] + pcnt[(size_t)b * NR + q] + (s2 - base[q]);
            int2 r = lrec[s2];
            rsrc[g] = r.x;
            rdst[g] = r.y;
        }
    }
}

// ==== CSR 5: per-range degree hist + row_ptr + deg-bins + COL PLACEMENT ===
__global__ __launch_bounds__(256) void deg_range_place(
    const int* __restrict__ rsrc, const int* __restrict__ rdst,
    const int* __restrict__ rstart,
    int* __restrict__ deg, int* __restrict__ row_ptr, int* __restrict__ phd,
    int* __restrict__ col, int n, int rdiv, int E)
{
    __shared__ int h[512];
    __shared__ int cur[512];
    __shared__ int psum[256];
    __shared__ int hd[256];
    int q = blockIdx.x, t = threadIdx.x;
    int lo = q * rdiv, hi = min(lo + rdiv, n);
    int nn = hi - lo;
    if (nn <= 0) {
        phd[q * 256 + t] = 0;
        if (t == 0 && q == NR - 1) row_ptr[n] = E;
        return;
    }
    h[t] = 0; h[t + 256] = 0; hd[t] = 0;
    __syncthreads();
    int rlo = rstart[q], rhi = rstart[q + 1];
    for (int i = rlo + t; i < rhi; i += 256)
        atomicAdd(&h[rdst[i] - lo], 1);
    __syncthreads();
    int s0 = h[2 * t], s1 = h[2 * t + 1];
    psum[t] = s0 + s1;
    __syncthreads();
    for (int off = 1; off < 256; off <<= 1) {
        int a = (t >= off) ? psum[t - off] : 0;
        __syncthreads();
        psum[t] += a;
        __syncthreads();
    }
    int base = rlo + ((t == 0) ? 0 : psum[t - 1]);
    cur[2 * t] = base;
    cur[2 * t + 1] = base + s0;
    if (2 * t < nn) {
        row_ptr[lo + 2 * t] = base;
        deg[lo + 2 * t] = s0;
        atomicAdd(&hd[min(s0, 255)], 1);
    }
    if (2 * t + 1 < nn) {
        row_ptr[lo + 2 * t + 1] = base + s0;
        deg[lo + 2 * t + 1] = s1;
        atomicAdd(&hd[min(s1, 255)], 1);
    }
    if (t == 0 && q == NR - 1) row_ptr[n] = E;
    __syncthreads();
    phd[q * 256 + t] = hd[t];
    for (int i = rlo + t; i < rhi; i += 256) {
        int pos = atomicAdd(&cur[rdst[i] - lo], 1);
        col[pos] = rsrc[i];
    }
}

// ==== degree sort A: per-bin scan over ranges (256 blocks, parallel) ======
__global__ __launch_bounds__(256) void dsort_scanA(
    int* __restrict__ phd, int* __restrict__ tot)
{
    __shared__ int tmp[256];
    int bin = blockIdx.x, t = threadIdx.x;
    int v = phd[t * 256 + bin];
    tmp[t] = v;
    __syncthreads();
    for (int off = 1; off < 256; off <<= 1) {
        int a = (t >= off) ? tmp[t - off] : 0;
        __syncthreads();
        tmp[t] += a;
        __syncthreads();
    }
    phd[t * 256 + bin] = tmp[t] - v;     // exclusive within-bin
    if (t == 255) tot[bin] = tmp[255];
}

// ==== degree sort B: exclusive scan of 256 bin totals (1 tiny block) ======
__global__ void dsort_scanB(int* __restrict__ tot)
{
    __shared__ int tmp[256];
    int t = threadIdx.x;
    int v = tot[t];
    tmp[t] = v;
    __syncthreads();
    for (int off = 1; off < 256; off <<= 1) {
        int a = (t >= off) ? tmp[t - off] : 0;
        __syncthreads();
        tmp[t] += a;
        __syncthreads();
    }
    tot[t] = tmp[t] - v;                 // exclusive bin base
}

// ==== degree sort C fused with ORDER placement ============================
__global__ __launch_bounds__(256) void dsort_place(
    const int* __restrict__ phd, const int* __restrict__ tot,
    const int* __restrict__ deg, int* __restrict__ order, int n, int rdiv)
{
    __shared__ int lcur[256];
    int q = blockIdx.x, t = threadIdx.x;
    lcur[t] = phd[q * 256 + t] + tot[t];
    __syncthreads();
    int lo = q * rdiv, hi = min(lo + rdiv, n);
    for (int i = lo + t; i < hi; i += 256) {
        int pos = atomicAdd(&lcur[min(deg[i], 255)], 1);
        order[pos] = i;
    }
}

// ==== pack W1 (4 x [128][32] fp32) into MFMA B-fragment order, bf16 =======
__global__ __launch_bounds__(256) void pack_w1(
    const float* __restrict__ Wq, const float* __restrict__ Wk,
    const float* __restrict__ Wv, const float* __restrict__ Ws,
    unsigned short* __restrict__ wp)
{
    int tid = blockIdx.x * 256 + threadIdx.x;   // 0..2047
    int s = tid >> 9, c = (tid >> 6) & 7, l = tid & 63;
    int gcol = c * 16 + (l & 15);
    int sub = gcol >> 5, j = gcol & 31;
    const float* W = (sub == 0) ? Wq : (sub == 1) ? Wk : (sub == 2) ? Wv : Ws;
    int k0 = s * 32 + ((l >> 4) << 3);
    unsigned short v[8];
    #pragma unroll
    for (int jj = 0; jj < 8; ++jj) v[jj] = f2bf(W[(size_t)(k0 + jj) * 32 + j]);
    uint4 o;
    o.x = v[0] | ((unsigned)v[1] << 16);
    o.y = v[2] | ((unsigned)v[3] << 16);
    o.z = v[4] | ((unsigned)v[5] << 16);
    o.w = v[6] | ((unsigned)v[7] << 16);
    *(uint4*)(wp + (size_t)tid * 8) = o;
}

// ==== pack W2 (4 x [32][16] fp32), frag idx: (c*64 + l), K=32 =============
__global__ void pack_w2(
    const float* __restrict__ Wq, const float* __restrict__ Wk,
    const float* __restrict__ Wv, const float* __restrict__ Ws,
    unsigned short* __restrict__ wp)
{
    int tid = threadIdx.x;                      // 0..255
    int c = tid >> 6, l = tid & 63;
    int gcol = c * 16 + (l & 15);
    int sub = gcol >> 4, j = gcol & 15;
    const float* W = (sub == 0) ? Wq : (sub == 1) ? Wk : (sub == 2) ? Wv : Ws;
    int k0 = (l >> 4) << 3;
    unsigned short v[8];
    #pragma unroll
    for (int jj = 0; jj < 8; ++jj) v[jj] = f2bf(W[(size_t)(k0 + jj) * 16 + j]);
    uint4 o;
    o.x = v[0] | ((unsigned)v[1] << 16);
    o.y = v[2] | ((unsigned)v[3] << 16);
    o.z = v[4] | ((unsigned)v[5] << 16);
    o.w = v[6] | ((unsigned)v[7] << 16);
    *(uint4*)(wp + (size_t)tid * 8) = o;
}

// ======== conv1 projection via MFMA: wave = 16 rows x 128 cols ============
// kvh1 HEAD-MAJOR (r18): kvh1[h][node] = 16B record (K8|V8 fp8).
// Per-head table = 1.6MB -> fits a 4MB per-XCD L2.
__global__ __launch_bounds__(256) void proj1_mfma(
    const float* __restrict__ x, const unsigned short* __restrict__ wp,
    const float* __restrict__ bq, const float* __restrict__ bk,
    const float* __restrict__ bv, const float* __restrict__ bs,
    float* __restrict__ qs1, unsigned char* __restrict__ kv1, int n)
{
    int w = threadIdx.x >> 6, l = threadIdx.x & 63;
    int row0 = blockIdx.x * 64 + w * 16;
    if (row0 >= n) return;
    int arow = row0 + (l & 15);
    f32x4 c0 = {0,0,0,0}, c1 = {0,0,0,0}, c2 = {0,0,0,0}, c3 = {0,0,0,0};
    f32x4 c4 = {0,0,0,0}, c5 = {0,0,0,0}, c6 = {0,0,0,0}, c7 = {0,0,0,0};
    const uint4* wp4 = (const uint4*)wp;
    #pragma unroll
    for (int s = 0; s < 4; ++s) {
        union { uint4 u; bf16x8 b; } av;
        if (arow < n) {
            const float* xp = x + (size_t)arow * 128 + s * 32 + ((l >> 4) << 3);
            float4 x0 = *(const float4*)xp;
            float4 x1 = *(const float4*)(xp + 4);
            av.u.x = f2bf(x0.x) | ((unsigned)f2bf(x0.y) << 16);
            av.u.y = f2bf(x0.z) | ((unsigned)f2bf(x0.w) << 16);
            av.u.z = f2bf(x1.x) | ((unsigned)f2bf(x1.y) << 16);
            av.u.w = f2bf(x1.z) | ((unsigned)f2bf(x1.w) << 16);
        } else {
            av.u = make_uint4(0, 0, 0, 0);
        }
        const uint4* base = wp4 + (size_t)(s * 8) * 64 + l;
        union { uint4 u; bf16x8 b; } bc;
        bc.u = base[0 * 64]; c0 = __builtin_amdgcn_mfma_f32_16x16x32_bf16(av.b, bc.b, c0, 0, 0, 0);
        bc.u = base[1 * 64]; c1 = __builtin_amdgcn_mfma_f32_16x16x32_bf16(av.b, bc.b, c1, 0, 0, 0);
        bc.u = base[2 * 64]; c2 = __builtin_amdgcn_mfma_f32_16x16x32_bf16(av.b, bc.b, c2, 0, 0, 0);
        bc.u = base[3 * 64]; c3 = __builtin_amdgcn_mfma_f32_16x16x32_bf16(av.b, bc.b, c3, 0, 0, 0);
        bc.u = base[4 * 64]; c4 = __builtin_amdgcn_mfma_f32_16x16x32_bf16(av.b, bc.b, c4, 0, 0, 0);
        bc.u = base[5 * 64]; c5 = __builtin_amdgcn_mfma_f32_16x16x32_bf16(av.b, bc.b, c5, 0, 0, 0);
        bc.u = base[6 * 64]; c6 = __builtin_amdgcn_mfma_f32_16x16x32_bf16(av.b, bc.b, c6, 0, 0, 0);
        bc.u = base[7 * 64]; c7 = __builtin_amdgcn_mfma_f32_16x16x32_bf16(av.b, bc.b, c7, 0, 0, 0);
    }
    int rbase = row0 + ((l >> 4) << 2);
    int lc = l & 15;
    int hA = lc >> 3, eA = lc & 7;       // K/V cols 0-15 -> heads 0,1
    int hB = 2 + (lc >> 3);              // K/V cols 16-31 -> heads 2,3
    float bq0 = bq[lc], bq1 = bq[16 + lc];
    float bk0 = bk[lc], bk1 = bk[16 + lc];
    float bv0 = bv[lc], bv1 = bv[16 + lc];
    float bs0 = bs[lc], bs1 = bs[16 + lc];
    #pragma unroll
    for (int r = 0; r < 4; ++r) {
        int row = rbase + r;
        if (row < n) {
            float* q = qs1 + (size_t)row * 64;
            q[lc]      = c0[r] + bq0;
            q[16 + lc] = c1[r] + bq1;
            q[32 + lc] = c6[r] + bs0;
            q[48 + lc] = c7[r] + bs1;
            kv1[((size_t)hA * n + row) * 16 + eA]     = f2fp8(c2[r] + bk0);
            kv1[((size_t)hB * n + row) * 16 + eA]     = f2fp8(c3[r] + bk1);
            kv1[((size_t)hA * n + row) * 16 + 8 + eA] = f2fp8(c4[r] + bv0);
            kv1[((size_t)hB * n + row) * 16 + 8 + eA] = f2fp8(c5[r] + bv1);
        }
    }
}

// ======== conv2 projection via MFMA: wave = 16 rows x 64 cols, K=32 =======
// kvh2 head-major: kvh2[h][node] = 8B record (K4|V4 fp8).
__global__ __launch_bounds__(256) void proj2_mfma(
    const float* __restrict__ h1, const unsigned short* __restrict__ wp,
    const float* __restrict__ bq, const float* __restrict__ bk,
    const float* __restrict__ bv, const float* __restrict__ bs,
    float* __restrict__ qs2, unsigned char* __restrict__ kv2, int n)
{
    int w = threadIdx.x >> 6, l = threadIdx.x & 63;
    int row0 = blockIdx.x * 64 + w * 16;
    if (row0 >= n) return;
    int arow = row0 + (l & 15);
    f32x4 c0 = {0,0,0,0}, c1 = {0,0,0,0}, c2 = {0,0,0,0}, c3 = {0,0,0,0};
    union { uint4 u; bf16x8 b; } av;
    if (arow < n) {
        const float* xp = h1 + (size_t)arow * 32 + ((l >> 4) << 3);
        float4 x0 = *(const float4*)xp;
        float4 x1 = *(const float4*)(xp + 4);
        av.u.x = f2bf(x0.x) | ((unsigned)f2bf(x0.y) << 16);
        av.u.y = f2bf(x0.z) | ((unsigned)f2bf(x0.w) << 16);
        av.u.z = f2bf(x1.x) | ((unsigned)f2bf(x1.y) << 16);
        av.u.w = f2bf(x1.z) | ((unsigned)f2bf(x1.w) << 16);
    } else {
        av.u = make_uint4(0, 0, 0, 0);
    }
    const uint4* base = (const uint4*)wp + l;
    union { uint4 u; bf16x8 b; } bc;
    bc.u = base[0];   c0 = __builtin_amdgcn_mfma_f32_16x16x32_bf16(av.b, bc.b, c0, 0, 0, 0);
    bc.u = base[64];  c1 = __builtin_amdgcn_mfma_f32_16x16x32_bf16(av.b, bc.b, c1, 0, 0, 0);
    bc.u = base[128]; c2 = __builtin_amdgcn_mfma_f32_16x16x32_bf16(av.b, bc.b, c2, 0, 0, 0);
    bc.u = base[192]; c3 = __builtin_amdgcn_mfma_f32_16x16x32_bf16(av.b, bc.b, c3, 0, 0, 0);
    int rbase = row0 + ((l >> 4) << 2);
    int lc = l & 15;
    int hh = lc >> 2, ee = lc & 3;
    float bq0 = bq[lc], bk0 = bk[lc], bv0 = bv[lc], bs0 = bs[lc];
    #pragma unroll
    for (int r = 0; r < 4; ++r) {
        int row = rbase + r;
        if (row < n) {
            float* q = qs2 + (size_t)row * 32;
            q[lc]      = c0[r] + bq0;
            q[16 + lc] = c3[r] + bs0;
            kv2[((size_t)hh * n + row) * 8 + ee]     = f2fp8(c1[r] + bk0);
            kv2[((size_t)hh * n + row) * 8 + 4 + ee] = f2fp8(c2[r] + bv0);
        }
    }
}

// ===== conv1 gather: HEAD-PARTITIONED blocks (h = bid&3 -> one head/XCD) ==
// Each XCD (bid%8) sees a single head's 1.6MB kv table -> L2-resident.
__global__ __launch_bounds__(256) void gather_conv1(
    const int* __restrict__ row_ptr, const int* __restrict__ order,
    const int* __restrict__ col, const float* __restrict__ qs1,
    const unsigned char* __restrict__ kv1, float* __restrict__ h1, int n)
{
    int h = blockIdx.x & 3;
    int idx = (blockIdx.x >> 2) * 256 + threadIdx.x;
    if (idx >= n) return;
    int node = order[idx];
    const unsigned char* kvh = kv1 + (size_t)h * n * 16;
    const float4* qp = (const float4*)(qs1 + (size_t)node * 64 + h * 8);
    float4 q0 = qp[0], q1 = qp[1];
    int start = row_ptr[node], d = row_ptr[node + 1] - start;
    float m = -INFINITY, s = 0.f;
    float a0x=0,a0y=0,a0z=0,a0w=0,a1x=0,a1y=0,a1z=0,a1w=0;
    if (d > 0) {
        int dm1 = d - 1;
        uint4 kv = *(const uint4*)(kvh + (size_t)col[start] * 16);
        int c1 = col[start + min(1, dm1)];
        for (int i = 0; i < d; ++i) {
            int c2 = col[start + min(i + 2, dm1)];
            uint4 kvn = *(const uint4*)(kvh + (size_t)c1 * 16);
            floatx2 k01 = __builtin_amdgcn_cvt_pk_f32_fp8(kv.x, false);
            floatx2 k23 = __builtin_amdgcn_cvt_pk_f32_fp8(kv.x, true);
            floatx2 k45 = __builtin_amdgcn_cvt_pk_f32_fp8(kv.y, false);
            floatx2 k67 = __builtin_amdgcn_cvt_pk_f32_fp8(kv.y, true);
            float a = (q0.x*k01.x + q0.y*k01.y + q0.z*k23.x + q0.w*k23.y
                     + q1.x*k45.x + q1.y*k45.y + q1.z*k67.x + q1.w*k67.y)
                    * 0.35355339059327373f;  // 1/sqrt(8)
            float mn = fmaxf(m, a);
            float corr = __expf(m - mn);   // first iter: exp(-inf)=0
            float ea = __expf(a - mn);
            s = s * corr + ea;
            floatx2 v01 = __builtin_amdgcn_cvt_pk_f32_fp8(kv.z, false);
            floatx2 v23 = __builtin_amdgcn_cvt_pk_f32_fp8(kv.z, true);
            floatx2 v45 = __builtin_amdgcn_cvt_pk_f32_fp8(kv.w, false);
            floatx2 v67 = __builtin_amdgcn_cvt_pk_f32_fp8(kv.w, true);
            a0x = a0x*corr + ea*v01.x; a0y = a0y*corr + ea*v01.y;
            a0z = a0z*corr + ea*v23.x; a0w = a0w*corr + ea*v23.y;
            a1x = a1x*corr + ea*v45.x; a1y = a1y*corr + ea*v45.y;
            a1z = a1z*corr + ea*v67.x; a1w = a1w*corr + ea*v67.y;
            m = mn;
            kv = kvn; c1 = c2;
        }
    }
    float inv = 1.f / (s + EPS);
    const float* sk = qs1 + (size_t)node * 64 + 32 + h * 8;
    float4 o0, o1;
    o0.x = fmaxf(a0x*inv + sk[0], 0.f); o0.y = fmaxf(a0y*inv + sk[1], 0.f);
    o0.z = fmaxf(a0z*inv + sk[2], 0.f); o0.w = fmaxf(a0w*inv + sk[3], 0.f);
    o1.x = fmaxf(a1x*inv + sk[4], 0.f); o1.y = fmaxf(a1y*inv + sk[5], 0.f);
    o1.z = fmaxf(a1z*inv + sk[6], 0.f); o1.w = fmaxf(a1w*inv + sk[7], 0.f);
    float4* op = (float4*)(h1 + (size_t)node * 32 + h * 8);
    op[0] = o0; op[1] = o1;
}

// ===== conv2 gather: head-partitioned, 8B kv records ======================
__global__ __launch_bounds__(256) void gather_conv2(
    const int* __restrict__ row_ptr, const int* __restrict__ order,
    const int* __restrict__ col, const float* __restrict__ qs2,
    const unsigned char* __restrict__ kv2, float* __restrict__ h2, int n)
{
    int h = blockIdx.x & 3;
    int idx = (blockIdx.x >> 2) * 256 + threadIdx.x;
    if (idx >= n) return;
    int node = order[idx];
    const unsigned char* kvh = kv2 + (size_t)h * n * 8;
    float4 q = *(const float4*)(qs2 + (size_t)node * 32 + h * 4);
    int start = row_ptr[node], d = row_ptr[node + 1] - start;
    float m = -INFINITY, s = 0.f;
    float ax=0, ay=0, az=0, aw=0;
    if (d > 0) {
        int dm1 = d - 1;
        uint2 kv = *(const uint2*)(kvh + (size_t)col[start] * 8);
        int c1 = col[start + min(1, dm1)];
        for (int i = 0; i < d; ++i) {
            int c2 = col[start + min(i + 2, dm1)];
            uint2 kvn = *(const uint2*)(kvh + (size_t)c1 * 8);
            floatx2 k01 = __builtin_amdgcn_cvt_pk_f32_fp8(kv.x, false);
            floatx2 k23 = __builtin_amdgcn_cvt_pk_f32_fp8(kv.x, true);
            float a = (q.x*k01.x + q.y*k01.y + q.z*k23.x + q.w*k23.y) * 0.5f;
            float mn = fmaxf(m, a);
            float corr = __expf(m - mn);
            float ea = __expf(a - mn);
            s = s * corr + ea;
            floatx2 v01 = __builtin_amdgcn_cvt_pk_f32_fp8(kv.y, false);
            floatx2 v23 = __builtin_amdgcn_cvt_pk_f32_fp8(kv.y, true);
            ax = ax*corr + ea*v01.x; ay = ay*corr + ea*v01.y;
            az = az*corr + ea*v23.x; aw = aw*corr + ea*v23.y;
            m = mn;
            kv = kvn; c1 = c2;
        }
    }
    float inv = 1.f / (s + EPS);
    const float* sk = qs2 + (size_t)node * 32 + 16 + h * 4;
    float4 o;
    o.x = fmaxf(ax*inv + sk[0], 0.f);
    o.y = fmaxf(ay*inv + sk[1], 0.f);
    o.z = fmaxf(az*inv + sk[2], 0.f);
    o.w = fmaxf(aw*inv + sk[3], 0.f);
    *(float4*)(h2 + (size_t)node * 16 + h * 4) = o;
}

// ====== mean-pool accumulation over h2 (block-local reduce, batch sorted) =
__global__ __launch_bounds__(256) void pool_kernel(
    const float* __restrict__ h2, const int* __restrict__ batch,
    float* __restrict__ pooled, float* __restrict__ cnt, int n)
{
    __shared__ float acc[16];
    __shared__ int bShared;
    __shared__ int uniform;
    int node0 = blockIdx.x * 16;
    int t = threadIdx.x;
    int node = node0 + (t >> 4), j = t & 15;
    if (t == 0) {
        int bFirst = batch[node0];
        int bLast = batch[min(node0 + 15, n - 1)];
        bShared = bFirst;
        uniform = (bFirst == bLast);
    }
    if (t < 16) acc[t] = 0.f;
    __syncthreads();
    bool active = node < n;
    float val = active ? h2[(size_t)node * 16 + j] : 0.f;
    if (uniform) {
        if (active) atomicAdd(&acc[j], val);
        __syncthreads();
        int nlocal = min(16, n - node0);
        if (t < 16) atomicAdd(pooled + bShared * 16 + t, acc[t]);
        if (t == 0) atomicAdd(cnt + bShared, (float)nlocal);
    } else {
        if (active) {
            int b = batch[node];
            atomicAdd(pooled + b * 16 + j, val);
            if (j == 0) atomicAdd(cnt + b, 1.f);
        }
    }
}

// ================= final FC on pooled [64,16] -> [64,10] ==================
__global__ void fc_kernel(
    const float* __restrict__ pooled, const float* __restrict__ cnt,
    const float* __restrict__ Wfc, const float* __restrict__ bfc,
    float* __restrict__ out)
{
    int t = threadIdx.x;
    if (t < 64 * 10) {
        int b = t / 10, o = t % 10;
        float c = fmaxf(cnt[b], 1.0f);
        float acc = bfc[o];
        #pragma unroll
        for (int k = 0; k < 16; ++k)
            acc += (pooled[b * 16 + k] / c) * Wfc[k * 10 + o];
        out[t] = acc;
    }
}

extern "C" void kernel_launch(void* const* d_in, const int* in_sizes, int n_in,
                              void* d_out, int out_size, void* d_ws, size_t ws_size,
                              hipStream_t stream) {
    const float* x     = (const float*)d_in[0];
    const int*   ei    = (const int*)d_in[1];
    const int*   batch = (const int*)d_in[2];
    const float* Wq1 = (const float*)d_in[3],  *bq1 = (const float*)d_in[4];
    const float* Wk1 = (const float*)d_in[5],  *bk1 = (const float*)d_in[6];
    const float* Wv1 = (const float*)d_in[7],  *bv1 = (const float*)d_in[8];
    const float* Ws1 = (const float*)d_in[9],  *bs1 = (const float*)d_in[10];
    const float* Wq2 = (const float*)d_in[11], *bq2 = (const float*)d_in[12];
    const float* Wk2 = (const float*)d_in[13], *bk2 = (const float*)d_in[14];
    const float* Wv2 = (const float*)d_in[15], *bv2 = (const float*)d_in[16];
    const float* Ws2 = (const float*)d_in[17], *bs2 = (const float*)d_in[18];
    const float* Wfc = (const float*)d_in[19], *bfc = (const float*)d_in[20];

    int N = in_sizes[0] / 128;
    int E = in_sizes[1] / 2;
    int rdiv = (N + NR - 1) / NR;            // 391 nodes per range
    float rinv = 1.0f / (float)rdiv;
    int NB = (E + EPB - 1) / EPB;            // scatter blocks

    // ---- workspace layout ----
    float* ws = (float*)d_ws;
    float* qs1    = ws;                                   // N*64 f  (q|s conv1)
    float* h1     = qs1 + (size_t)N * 64;                 // N*32 f  (aliased rsrc)
    float* h2     = h1 + (size_t)N * 32;                  // N*16 f  (aliased rdst lo)
    float* qs2    = h2 + (size_t)N * 16;                  // N*32 f  (rdst overflow)
    float* pooled = qs2 + (size_t)N * 32;                 // 1024 f
    float* cnt    = pooled + 1024;                        // 64 f
    unsigned char* kv1 = (unsigned char*)(cnt + 64);      // 4 x N x 16B head-major
    unsigned char* kv2 = kv1 + (size_t)N * 64;            // 4 x N x 8B head-major
    int* deg     = (int*)(kv2 + (size_t)N * 32);          // N
    int* row_ptr = deg + N;                               // N+1 (sentinel)
    int* rstart  = row_ptr + N + 1;                       // NR+1
    int* qtot    = rstart + NR + 1;                       // NR (reused as dsort tot)
    int* col     = qtot + NR;                             // E
    int* order   = col + E;                               // N
    int* pcnt    = order + N;                             // NB*NR
    int* phd     = pcnt + (size_t)NB * NR;                // NR*256
    unsigned short* wp1 = (unsigned short*)(phd + (size_t)NR * 256); // 16384 bf16
    unsigned short* wp2 = wp1 + 16384;                    // 2048 bf16
    int* rsrc = (int*)h1;                                 // E ints (N*32 == E)
    int* rdst = (int*)h2;                                 // E ints (spills into qs2)

    // zero: pooled + cnt accumulators only (everything else fully written)
    hipMemsetAsync(pooled, 0, (1024 + 64) * sizeof(float), stream);

    int ggrid = 4 * ((N + 255) / 256);       // head-partitioned gather grid
    int mtiles = (N + 63) / 64;

    // ---- weight packing (independent, tiny) ----
    pack_w1<<<8, 256, 0, stream>>>(Wq1, Wk1, Wv1, Ws1, wp1);
    pack_w2<<<1, 256, 0, stream>>>(Wq2, Wk2, Wv2, Ws2, wp2);

    // ---- CSR build + fused degree sort (LDS atomics only) ----
    scatter_count<<<NB, 256, 0, stream>>>(ei, E, rdiv, rinv, pcnt);
    qprefix<<<NR, 256, 0, stream>>>(pcnt, NB, qtot);
    qscan<<<1, NR, 0, stream>>>(qtot, rstart);
    scatter_place<<<NB, 256, 0, stream>>>(ei, E, rdiv, rinv, pcnt, rstart, rsrc, rdst);
    deg_range_place<<<NR, 256, 0, stream>>>(rsrc, rdst, rstart, deg, row_ptr, phd, col, N, rdiv, E);
    dsort_scanA<<<NR, 256, 0, stream>>>(phd, qtot);
    dsort_scanB<<<1, 256, 0, stream>>>(qtot);
    dsort_place<<<NR, 256, 0, stream>>>(phd, qtot, deg, order, N, rdiv);

    // ---- conv1 ----
    proj1_mfma<<<mtiles, 256, 0, stream>>>(x, wp1, bq1, bk1, bv1, bs1, qs1, kv1, N);
    gather_conv1<<<ggrid, 256, 0, stream>>>(row_ptr, order, col, qs1, kv1, h1, N);

    // ---- conv2 ----
    proj2_mfma<<<mtiles, 256, 0, stream>>>(h1, wp2, bq2, bk2, bv2, bs2, qs2, kv2, N);
    gather_conv2<<<ggrid, 256, 0, stream>>>(row_ptr, order, col, qs2, kv2, h2, N);

    // ---- pool + fc ----
    pool_kernel<<<(N + 15) / 16, 256, 0, stream>>>(h2, batch, pooled, cnt, N);
    fc_kernel<<<1, 640, 0, stream>>>(pooled, cnt, Wfc, bfc, (float*)d_out);
}

// Round 20
// 309.629 us; speedup vs baseline: 2.2792x; 2.2792x over previous
//
#include <hip/hip_runtime.h>

#define HEADS 4
#define EPS 1e-16f
#define NR 256    // dst ranges (counting-sort buckets)
#define EPB 2048  // edges per scatter block

typedef float floatx2 __attribute__((ext_vector_type(2)));
typedef short bf16x8 __attribute__((ext_vector_type(8)));
typedef float f32x4 __attribute__((ext_vector_type(4)));

// bf16 RNE pack
__device__ inline unsigned short f2bf(float f) {
    union { float f; unsigned u; } v; v.f = f;
    unsigned r = v.u + 0x7FFFu + ((v.u >> 16) & 1u);
    return (unsigned short)(r >> 16);
}
__device__ inline unsigned char f2fp8(float f) {
    return (unsigned char)(__builtin_amdgcn_cvt_pk_fp8_f32(f, 0.f, 0u, false) & 0xFF);
}

// exact dst-range classifier: q = dst / rdiv (float approx + integer fix)
__device__ inline int rangeOf(int dst, int rdiv, float rinv) {
    int q = (int)((float)dst * rinv);
    if (q > NR - 1) q = NR - 1;
    if ((long long)q * rdiv > dst) --q;
    else if ((long long)(q + 1) * rdiv <= dst) ++q;
    return q;
}

// ==== CSR 1: per-(block,range) counts. LDS atomics only ===================
__global__ __launch_bounds__(256) void scatter_count(
    const int* __restrict__ ei, int E, int rdiv, float rinv,
    int* __restrict__ pcnt)
{
    __shared__ int cnt[NR];
    int b = blockIdx.x, t = threadIdx.x;
    int b0 = b * EPB;
    int nloc = min(EPB, E - b0);
    cnt[t] = 0;
    __syncthreads();
    #pragma unroll
    for (int u = 0; u < 8; ++u) {
        int li = u * 256 + t;
        if (li < nloc)
            atomicAdd(&cnt[rangeOf(ei[E + b0 + li], rdiv, rinv)], 1);
    }
    __syncthreads();
    pcnt[(size_t)b * NR + t] = cnt[t];
}

// ==== CSR 2: per-range prefix over blocks (pcnt -> within-range offsets) ==
__global__ __launch_bounds__(256) void qprefix(
    int* __restrict__ pcnt, int nb, int* __restrict__ qtot)
{
    __shared__ int part[256];
    int q = blockIdx.x, t = threadIdx.x;
    int per = (nb + 255) >> 8;
    int lo = t * per, hi = min(lo + per, nb);
    int s = 0;
    for (int b = lo; b < hi; ++b) s += pcnt[(size_t)b * NR + q];
    part[t] = s;
    __syncthreads();
    for (int off = 1; off < 256; off <<= 1) {
        int a = (t >= off) ? part[t - off] : 0;
        __syncthreads();
        part[t] += a;
        __syncthreads();
    }
    if (t == 255) qtot[q] = part[255];
    int pre = (t == 0) ? 0 : part[t - 1];
    for (int b = lo; b < hi; ++b) {
        int c = pcnt[(size_t)b * NR + q];
        pcnt[(size_t)b * NR + q] = pre;
        pre += c;
    }
}

// ==== CSR 3: scan 256 range totals -> rstart[NR+1] ========================
__global__ void qscan(const int* __restrict__ qtot, int* __restrict__ rstart)
{
    __shared__ int tmp[NR];
    int t = threadIdx.x;
    tmp[t] = qtot[t];
    __syncthreads();
    for (int off = 1; off < NR; off <<= 1) {
        int a = (t >= off) ? tmp[t - off] : 0;
        __syncthreads();
        tmp[t] += a;
        __syncthreads();
    }
    rstart[t] = (t == 0) ? 0 : tmp[t - 1];
    if (t == NR - 1) rstart[NR] = tmp[NR - 1];
}

// ==== CSR 4: place edges into range-grouped SoA. No global atomics ========
__global__ __launch_bounds__(256) void scatter_place(
    const int* __restrict__ ei, int E, int rdiv, float rinv,
    const int* __restrict__ pcnt, const int* __restrict__ rstart,
    int* __restrict__ rsrc, int* __restrict__ rdst)
{
    __shared__ int2 lrec[EPB];
    __shared__ unsigned char lq[EPB];
    __shared__ int cnt[NR], base[NR], scn[NR];
    int b = blockIdx.x, t = threadIdx.x;
    int b0 = b * EPB;
    int nloc = min(EPB, E - b0);
    cnt[t] = 0;
    __syncthreads();
    int myq[8], myoff[8];
    int2 myrec[8];
    #pragma unroll
    for (int u = 0; u < 8; ++u) {
        int li = u * 256 + t;
        if (li < nloc) {
            int e = b0 + li;
            int sv = ei[e], dv = ei[E + e];
            int q = rangeOf(dv, rdiv, rinv);
            myq[u] = q;
            myrec[u] = make_int2(sv, dv);
            myoff[u] = atomicAdd(&cnt[q], 1);
        } else myq[u] = -1;
    }
    __syncthreads();
    scn[t] = cnt[t];
    __syncthreads();
    for (int off = 1; off < 256; off <<= 1) {
        int a = (t >= off) ? scn[t - off] : 0;
        __syncthreads();
        scn[t] += a;
        __syncthreads();
    }
    base[t] = (t == 0) ? 0 : scn[t - 1];
    __syncthreads();
    #pragma unroll
    for (int u = 0; u < 8; ++u) {
        if (myq[u] >= 0) {
            int slot = base[myq[u]] + myoff[u];
            lrec[slot] = myrec[u];
            lq[slot] = (unsigned char)myq[u];
        }
    }
    __syncthreads();
    #pragma unroll
    for (int u = 0; u < 8; ++u) {
        int s2 = u * 256 + t;
        if (s2 < nloc) {
            int q = lq[s2];
            int g = rstart[q] + pcnt[(size_t)b * NR + q] + (s2 - base[q]);
            int2 r = lrec[s2];
            rsrc[g] = r.x;
            rdst[g] = r.y;
        }
    }
}

// ==== CSR 5: per-range degree hist + row_ptr + deg-bins + COL PLACEMENT ===
__global__ __launch_bounds__(256) void deg_range_place(
    const int* __restrict__ rsrc, const int* __restrict__ rdst,
    const int* __restrict__ rstart,
    int* __restrict__ deg, int* __restrict__ row_ptr, int* __restrict__ phd,
    int* __restrict__ col, int n, int rdiv, int E)
{
    __shared__ int h[512];
    __shared__ int cur[512];
    __shared__ int psum[256];
    __shared__ int hd[256];
    int q = blockIdx.x, t = threadIdx.x;
    int lo = q * rdiv, hi = min(lo + rdiv, n);
    int nn = hi - lo;
    if (nn <= 0) {
        phd[q * 256 + t] = 0;
        if (t == 0 && q == NR - 1) row_ptr[n] = E;
        return;
    }
    h[t] = 0; h[t + 256] = 0; hd[t] = 0;
    __syncthreads();
    int rlo = rstart[q], rhi = rstart[q + 1];
    for (int i = rlo + t; i < rhi; i += 256)
        atomicAdd(&h[rdst[i] - lo], 1);
    __syncthreads();
    int s0 = h[2 * t], s1 = h[2 * t + 1];
    psum[t] = s0 + s1;
    __syncthreads();
    for (int off = 1; off < 256; off <<= 1) {
        int a = (t >= off) ? psum[t - off] : 0;
        __syncthreads();
        psum[t] += a;
        __syncthreads();
    }
    int base = rlo + ((t == 0) ? 0 : psum[t - 1]);
    cur[2 * t] = base;
    cur[2 * t + 1] = base + s0;
    if (2 * t < nn) {
        row_ptr[lo + 2 * t] = base;
        deg[lo + 2 * t] = s0;
        atomicAdd(&hd[min(s0, 255)], 1);
    }
    if (2 * t + 1 < nn) {
        row_ptr[lo + 2 * t + 1] = base + s0;
        deg[lo + 2 * t + 1] = s1;
        atomicAdd(&hd[min(s1, 255)], 1);
    }
    if (t == 0 && q == NR - 1) row_ptr[n] = E;
    __syncthreads();
    phd[q * 256 + t] = hd[t];
    for (int i = rlo + t; i < rhi; i += 256) {
        int pos = atomicAdd(&cur[rdst[i] - lo], 1);
        col[pos] = rsrc[i];
    }
}

// ==== degree sort A: per-bin scan over ranges (256 blocks, parallel) ======
__global__ __launch_bounds__(256) void dsort_scanA(
    int* __restrict__ phd, int* __restrict__ tot)
{
    __shared__ int tmp[256];
    int bin = blockIdx.x, t = threadIdx.x;
    int v = phd[t * 256 + bin];
    tmp[t] = v;
    __syncthreads();
    for (int off = 1; off < 256; off <<= 1) {
        int a = (t >= off) ? tmp[t - off] : 0;
        __syncthreads();
        tmp[t] += a;
        __syncthreads();
    }
    phd[t * 256 + bin] = tmp[t] - v;     // exclusive within-bin
    if (t == 255) tot[bin] = tmp[255];
}

// ==== degree sort B: exclusive scan of 256 bin totals (1 tiny block) ======
__global__ void dsort_scanB(int* __restrict__ tot)
{
    __shared__ int tmp[256];
    int t = threadIdx.x;
    int v = tot[t];
    tmp[t] = v;
    __syncthreads();
    for (int off = 1; off < 256; off <<= 1) {
        int a = (t >= off) ? tmp[t - off] : 0;
        __syncthreads();
        tmp[t] += a;
        __syncthreads();
    }
    tot[t] = tmp[t] - v;                 // exclusive bin base
}

// ==== degree sort C fused with ORDER placement ============================
__global__ __launch_bounds__(256) void dsort_place(
    const int* __restrict__ phd, const int* __restrict__ tot,
    const int* __restrict__ deg, int* __restrict__ order, int n, int rdiv)
{
    __shared__ int lcur[256];
    int q = blockIdx.x, t = threadIdx.x;
    lcur[t] = phd[q * 256 + t] + tot[t];
    __syncthreads();
    int lo = q * rdiv, hi = min(lo + rdiv, n);
    for (int i = lo + t; i < hi; i += 256) {
        int pos = atomicAdd(&lcur[min(deg[i], 255)], 1);
        order[pos] = i;
    }
}

// ==== pack W1 (4 x [128][32] fp32) into MFMA B-fragment order, bf16 =======
__global__ __launch_bounds__(256) void pack_w1(
    const float* __restrict__ Wq, const float* __restrict__ Wk,
    const float* __restrict__ Wv, const float* __restrict__ Ws,
    unsigned short* __restrict__ wp)
{
    int tid = blockIdx.x * 256 + threadIdx.x;   // 0..2047
    int s = tid >> 9, c = (tid >> 6) & 7, l = tid & 63;
    int gcol = c * 16 + (l & 15);
    int sub = gcol >> 5, j = gcol & 31;
    const float* W = (sub == 0) ? Wq : (sub == 1) ? Wk : (sub == 2) ? Wv : Ws;
    int k0 = s * 32 + ((l >> 4) << 3);
    unsigned short v[8];
    #pragma unroll
    for (int jj = 0; jj < 8; ++jj) v[jj] = f2bf(W[(size_t)(k0 + jj) * 32 + j]);
    uint4 o;
    o.x = v[0] | ((unsigned)v[1] << 16);
    o.y = v[2] | ((unsigned)v[3] << 16);
    o.z = v[4] | ((unsigned)v[5] << 16);
    o.w = v[6] | ((unsigned)v[7] << 16);
    *(uint4*)(wp + (size_t)tid * 8) = o;
}

// ==== pack W2 (4 x [32][16] fp32), frag idx: (c*64 + l), K=32 =============
__global__ void pack_w2(
    const float* __restrict__ Wq, const float* __restrict__ Wk,
    const float* __restrict__ Wv, const float* __restrict__ Ws,
    unsigned short* __restrict__ wp)
{
    int tid = threadIdx.x;                      // 0..255
    int c = tid >> 6, l = tid & 63;
    int gcol = c * 16 + (l & 15);
    int sub = gcol >> 4, j = gcol & 15;
    const float* W = (sub == 0) ? Wq : (sub == 1) ? Wk : (sub == 2) ? Wv : Ws;
    int k0 = (l >> 4) << 3;
    unsigned short v[8];
    #pragma unroll
    for (int jj = 0; jj < 8; ++jj) v[jj] = f2bf(W[(size_t)(k0 + jj) * 16 + j]);
    uint4 o;
    o.x = v[0] | ((unsigned)v[1] << 16);
    o.y = v[2] | ((unsigned)v[3] << 16);
    o.z = v[4] | ((unsigned)v[5] << 16);
    o.w = v[6] | ((unsigned)v[7] << 16);
    *(uint4*)(wp + (size_t)tid * 8) = o;
}

// ======== conv1 projection via MFMA: wave = 16 rows x 128 cols ============
// kv1 written HEAD-INTERLEAVED: node record = [h: K8B | V8B] x4,
// so the gather reads ONE uint4 per edge.
__global__ __launch_bounds__(256) void proj1_mfma(
    const float* __restrict__ x, const unsigned short* __restrict__ wp,
    const float* __restrict__ bq, const float* __restrict__ bk,
    const float* __restrict__ bv, const float* __restrict__ bs,
    float* __restrict__ qs1, unsigned char* __restrict__ kv1, int n)
{
    int w = threadIdx.x >> 6, l = threadIdx.x & 63;
    int row0 = blockIdx.x * 64 + w * 16;
    if (row0 >= n) return;
    int arow = row0 + (l & 15);
    f32x4 c0 = {0,0,0,0}, c1 = {0,0,0,0}, c2 = {0,0,0,0}, c3 = {0,0,0,0};
    f32x4 c4 = {0,0,0,0}, c5 = {0,0,0,0}, c6 = {0,0,0,0}, c7 = {0,0,0,0};
    const uint4* wp4 = (const uint4*)wp;
    #pragma unroll
    for (int s = 0; s < 4; ++s) {
        union { uint4 u; bf16x8 b; } av;
        if (arow < n) {
            const float* xp = x + (size_t)arow * 128 + s * 32 + ((l >> 4) << 3);
            float4 x0 = *(const float4*)xp;
            float4 x1 = *(const float4*)(xp + 4);
            av.u.x = f2bf(x0.x) | ((unsigned)f2bf(x0.y) << 16);
            av.u.y = f2bf(x0.z) | ((unsigned)f2bf(x0.w) << 16);
            av.u.z = f2bf(x1.x) | ((unsigned)f2bf(x1.y) << 16);
            av.u.w = f2bf(x1.z) | ((unsigned)f2bf(x1.w) << 16);
        } else {
            av.u = make_uint4(0, 0, 0, 0);
        }
        const uint4* base = wp4 + (size_t)(s * 8) * 64 + l;
        union { uint4 u; bf16x8 b; } bc;
        bc.u = base[0 * 64]; c0 = __builtin_amdgcn_mfma_f32_16x16x32_bf16(av.b, bc.b, c0, 0, 0, 0);
        bc.u = base[1 * 64]; c1 = __builtin_amdgcn_mfma_f32_16x16x32_bf16(av.b, bc.b, c1, 0, 0, 0);
        bc.u = base[2 * 64]; c2 = __builtin_amdgcn_mfma_f32_16x16x32_bf16(av.b, bc.b, c2, 0, 0, 0);
        bc.u = base[3 * 64]; c3 = __builtin_amdgcn_mfma_f32_16x16x32_bf16(av.b, bc.b, c3, 0, 0, 0);
        bc.u = base[4 * 64]; c4 = __builtin_amdgcn_mfma_f32_16x16x32_bf16(av.b, bc.b, c4, 0, 0, 0);
        bc.u = base[5 * 64]; c5 = __builtin_amdgcn_mfma_f32_16x16x32_bf16(av.b, bc.b, c5, 0, 0, 0);
        bc.u = base[6 * 64]; c6 = __builtin_amdgcn_mfma_f32_16x16x32_bf16(av.b, bc.b, c6, 0, 0, 0);
        bc.u = base[7 * 64]; c7 = __builtin_amdgcn_mfma_f32_16x16x32_bf16(av.b, bc.b, c7, 0, 0, 0);
    }
    int rbase = row0 + ((l >> 4) << 2);
    int lc = l & 15;
    // interleaved positions for K col lc / 16+lc and V col lc / 16+lc
    int pkA = ((lc >> 3) << 4) + (lc & 7);           // K cols 0-15
    int pkB = ((2 + (lc >> 3)) << 4) + (lc & 7);     // K cols 16-31
    int pvA = pkA + 8;                                // V cols 0-15
    int pvB = pkB + 8;                                // V cols 16-31
    float bq0 = bq[lc], bq1 = bq[16 + lc];
    float bk0 = bk[lc], bk1 = bk[16 + lc];
    float bv0 = bv[lc], bv1 = bv[16 + lc];
    float bs0 = bs[lc], bs1 = bs[16 + lc];
    #pragma unroll
    for (int r = 0; r < 4; ++r) {
        int row = rbase + r;
        if (row < n) {
            float* q = qs1 + (size_t)row * 64;
            unsigned char* kvp = kv1 + (size_t)row * 64;
            q[lc]      = c0[r] + bq0;
            q[16 + lc] = c1[r] + bq1;
            q[32 + lc] = c6[r] + bs0;
            q[48 + lc] = c7[r] + bs1;
            kvp[pkA] = f2fp8(c2[r] + bk0);
            kvp[pkB] = f2fp8(c3[r] + bk1);
            kvp[pvA] = f2fp8(c4[r] + bv0);
            kvp[pvB] = f2fp8(c5[r] + bv1);
        }
    }
}

// ======== conv2 projection via MFMA: wave = 16 rows x 64 cols, K=32 =======
// kv2 head-interleaved: node record = [h: K4B | V4B] x4 (32B).
__global__ __launch_bounds__(256) void proj2_mfma(
    const float* __restrict__ h1, const unsigned short* __restrict__ wp,
    const float* __restrict__ bq, const float* __restrict__ bk,
    const float* __restrict__ bv, const float* __restrict__ bs,
    float* __restrict__ qs2, unsigned char* __restrict__ kv2, int n)
{
    int w = threadIdx.x >> 6, l = threadIdx.x & 63;
    int row0 = blockIdx.x * 64 + w * 16;
    if (row0 >= n) return;
    int arow = row0 + (l & 15);
    f32x4 c0 = {0,0,0,0}, c1 = {0,0,0,0}, c2 = {0,0,0,0}, c3 = {0,0,0,0};
    union { uint4 u; bf16x8 b; } av;
    if (arow < n) {
        const float* xp = h1 + (size_t)arow * 32 + ((l >> 4) << 3);
        float4 x0 = *(const float4*)xp;
        float4 x1 = *(const float4*)(xp + 4);
        av.u.x = f2bf(x0.x) | ((unsigned)f2bf(x0.y) << 16);
        av.u.y = f2bf(x0.z) | ((unsigned)f2bf(x0.w) << 16);
        av.u.z = f2bf(x1.x) | ((unsigned)f2bf(x1.y) << 16);
        av.u.w = f2bf(x1.z) | ((unsigned)f2bf(x1.w) << 16);
    } else {
        av.u = make_uint4(0, 0, 0, 0);
    }
    const uint4* base = (const uint4*)wp + l;
    union { uint4 u; bf16x8 b; } bc;
    bc.u = base[0];   c0 = __builtin_amdgcn_mfma_f32_16x16x32_bf16(av.b, bc.b, c0, 0, 0, 0);
    bc.u = base[64];  c1 = __builtin_amdgcn_mfma_f32_16x16x32_bf16(av.b, bc.b, c1, 0, 0, 0);
    bc.u = base[128]; c2 = __builtin_amdgcn_mfma_f32_16x16x32_bf16(av.b, bc.b, c2, 0, 0, 0);
    bc.u = base[192]; c3 = __builtin_amdgcn_mfma_f32_16x16x32_bf16(av.b, bc.b, c3, 0, 0, 0);
    int rbase = row0 + ((l >> 4) << 2);
    int lc = l & 15;
    int pk = ((lc >> 2) << 3) + (lc & 3);     // K col lc interleaved pos
    int pv = pk + 4;                           // V col lc
    float bq0 = bq[lc], bk0 = bk[lc], bv0 = bv[lc], bs0 = bs[lc];
    #pragma unroll
    for (int r = 0; r < 4; ++r) {
        int row = rbase + r;
        if (row < n) {
            float* q = qs2 + (size_t)row * 32;
            unsigned char* kvp = kv2 + (size_t)row * 32;
            q[lc]      = c0[r] + bq0;
            q[16 + lc] = c3[r] + bs0;
            kvp[pk] = f2fp8(c1[r] + bk0);
            kvp[pv] = f2fp8(c2[r] + bv0);
        }
    }
}

// ===== conv1 fused gather: interleaved KV = ONE uint4 load per edge =======
__global__ __launch_bounds__(256) void gather_conv1(
    const int* __restrict__ row_ptr, const int* __restrict__ order,
    const int* __restrict__ col, const float* __restrict__ qs1,
    const unsigned char* __restrict__ kv1, float* __restrict__ h1, int n)
{
    int tid = blockIdx.x * 256 + threadIdx.x;
    if (tid >= n * HEADS) return;
    int node = order[tid >> 2], h = tid & 3;
    const float4* qp = (const float4*)(qs1 + (size_t)node * 64 + h * 8);
    float4 q0 = qp[0], q1 = qp[1];
    int start = row_ptr[node], d = row_ptr[node + 1] - start;
    float m = -INFINITY, s = 0.f;
    float a0x=0,a0y=0,a0z=0,a0w=0,a1x=0,a1y=0,a1z=0,a1w=0;
    if (d > 0) {
        int dm1 = d - 1;
        uint4 kv = *(const uint4*)(kv1 + (size_t)col[start] * 64 + h * 16);
        int c1 = col[start + min(1, dm1)];
        for (int i = 0; i < d; ++i) {
            int c2 = col[start + min(i + 2, dm1)];
            uint4 kvn = *(const uint4*)(kv1 + (size_t)c1 * 64 + h * 16);
            floatx2 k01 = __builtin_amdgcn_cvt_pk_f32_fp8(kv.x, false);
            floatx2 k23 = __builtin_amdgcn_cvt_pk_f32_fp8(kv.x, true);
            floatx2 k45 = __builtin_amdgcn_cvt_pk_f32_fp8(kv.y, false);
            floatx2 k67 = __builtin_amdgcn_cvt_pk_f32_fp8(kv.y, true);
            float a = (q0.x*k01.x + q0.y*k01.y + q0.z*k23.x + q0.w*k23.y
                     + q1.x*k45.x + q1.y*k45.y + q1.z*k67.x + q1.w*k67.y)
                    * 0.35355339059327373f;  // 1/sqrt(8)
            float mn = fmaxf(m, a);
            float corr = __expf(m - mn);   // first iter: exp(-inf)=0
            float ea = __expf(a - mn);
            s = s * corr + ea;
            floatx2 v01 = __builtin_amdgcn_cvt_pk_f32_fp8(kv.z, false);
            floatx2 v23 = __builtin_amdgcn_cvt_pk_f32_fp8(kv.z, true);
            floatx2 v45 = __builtin_amdgcn_cvt_pk_f32_fp8(kv.w, false);
            floatx2 v67 = __builtin_amdgcn_cvt_pk_f32_fp8(kv.w, true);
            a0x = a0x*corr + ea*v01.x; a0y = a0y*corr + ea*v01.y;
            a0z = a0z*corr + ea*v23.x; a0w = a0w*corr + ea*v23.y;
            a1x = a1x*corr + ea*v45.x; a1y = a1y*corr + ea*v45.y;
            a1z = a1z*corr + ea*v67.x; a1w = a1w*corr + ea*v67.y;
            m = mn;
            kv = kvn; c1 = c2;
        }
    }
    float inv = 1.f / (s + EPS);
    const float* sk = qs1 + (size_t)node * 64 + 32 + h * 8;
    float4 o0, o1;
    o0.x = fmaxf(a0x*inv + sk[0], 0.f); o0.y = fmaxf(a0y*inv + sk[1], 0.f);
    o0.z = fmaxf(a0z*inv + sk[2], 0.f); o0.w = fmaxf(a0w*inv + sk[3], 0.f);
    o1.x = fmaxf(a1x*inv + sk[4], 0.f); o1.y = fmaxf(a1y*inv + sk[5], 0.f);
    o1.z = fmaxf(a1z*inv + sk[6], 0.f); o1.w = fmaxf(a1w*inv + sk[7], 0.f);
    float4* op = (float4*)(h1 + (size_t)node * 32 + h * 8);
    op[0] = o0; op[1] = o1;
}

// ===== conv2 fused gather: interleaved KV = ONE uint2 load per edge =======
__global__ __launch_bounds__(256) void gather_conv2(
    const int* __restrict__ row_ptr, const int* __restrict__ order,
    const int* __restrict__ col, const float* __restrict__ qs2,
    const unsigned char* __restrict__ kv2, float* __restrict__ h2, int n)
{
    int tid = blockIdx.x * 256 + threadIdx.x;
    if (tid >= n * HEADS) return;
    int node = order[tid >> 2], h = tid & 3;
    float4 q = *(const float4*)(qs2 + (size_t)node * 32 + h * 4);
    int start = row_ptr[node], d = row_ptr[node + 1] - start;
    float m = -INFINITY, s = 0.f;
    float ax=0, ay=0, az=0, aw=0;
    if (d > 0) {
        int dm1 = d - 1;
        uint2 kv = *(const uint2*)(kv2 + (size_t)col[start] * 32 + h * 8);
        int c1 = col[start + min(1, dm1)];
        for (int i = 0; i < d; ++i) {
            int c2 = col[start + min(i + 2, dm1)];
            uint2 kvn = *(const uint2*)(kv2 + (size_t)c1 * 32 + h * 8);
            floatx2 k01 = __builtin_amdgcn_cvt_pk_f32_fp8(kv.x, false);
            floatx2 k23 = __builtin_amdgcn_cvt_pk_f32_fp8(kv.x, true);
            float a = (q.x*k01.x + q.y*k01.y + q.z*k23.x + q.w*k23.y) * 0.5f;
            float mn = fmaxf(m, a);
            float corr = __expf(m - mn);
            float ea = __expf(a - mn);
            s = s * corr + ea;
            floatx2 v01 = __builtin_amdgcn_cvt_pk_f32_fp8(kv.y, false);
            floatx2 v23 = __builtin_amdgcn_cvt_pk_f32_fp8(kv.y, true);
            ax = ax*corr + ea*v01.x; ay = ay*corr + ea*v01.y;
            az = az*corr + ea*v23.x; aw = aw*corr + ea*v23.y;
            m = mn;
            kv = kvn; c1 = c2;
        }
    }
    float inv = 1.f / (s + EPS);
    const float* sk = qs2 + (size_t)node * 32 + 16 + h * 4;
    float4 o;
    o.x = fmaxf(ax*inv + sk[0], 0.f);
    o.y = fmaxf(ay*inv + sk[1], 0.f);
    o.z = fmaxf(az*inv + sk[2], 0.f);
    o.w = fmaxf(aw*inv + sk[3], 0.f);
    *(float4*)(h2 + (size_t)node * 16 + h * 4) = o;
}

// ====== mean-pool accumulation over h2 (block-local reduce, batch sorted) =
__global__ __launch_bounds__(256) void pool_kernel(
    const float* __restrict__ h2, const int* __restrict__ batch,
    float* __restrict__ pooled, float* __restrict__ cnt, int n)
{
    __shared__ float acc[16];
    __shared__ int bShared;
    __shared__ int uniform;
    int node0 = blockIdx.x * 16;
    int t = threadIdx.x;
    int node = node0 + (t >> 4), j = t & 15;
    if (t == 0) {
        int bFirst = batch[node0];
        int bLast = batch[min(node0 + 15, n - 1)];
        bShared = bFirst;
        uniform = (bFirst == bLast);
    }
    if (t < 16) acc[t] = 0.f;
    __syncthreads();
    bool active = node < n;
    float val = active ? h2[(size_t)node * 16 + j] : 0.f;
    if (uniform) {
        if (active) atomicAdd(&acc[j], val);
        __syncthreads();
        int nlocal = min(16, n - node0);
        if (t < 16) atomicAdd(pooled + bShared * 16 + t, acc[t]);
        if (t == 0) atomicAdd(cnt + bShared, (float)nlocal);
    } else {
        if (active) {
            int b = batch[node];
            atomicAdd(pooled + b * 16 + j, val);
            if (j == 0) atomicAdd(cnt + b, 1.f);
        }
    }
}

// ================= final FC on pooled [64,16] -> [64,10] ==================
__global__ void fc_kernel(
    const float* __restrict__ pooled, const float* __restrict__ cnt,
    const float* __restrict__ Wfc, const float* __restrict__ bfc,
    float* __restrict__ out)
{
    int t = threadIdx.x;
    if (t < 64 * 10) {
        int b = t / 10, o = t % 10;
        float c = fmaxf(cnt[b], 1.0f);
        float acc = bfc[o];
        #pragma unroll
        for (int k = 0; k < 16; ++k)
            acc += (pooled[b * 16 + k] / c) * Wfc[k * 10 + o];
        out[t] = acc;
    }
}

extern "C" void kernel_launch(void* const* d_in, const int* in_sizes, int n_in,
                              void* d_out, int out_size, void* d_ws, size_t ws_size,
                              hipStream_t stream) {
    const float* x     = (const float*)d_in[0];
    const int*   ei    = (const int*)d_in[1];
    const int*   batch = (const int*)d_in[2];
    const float* Wq1 = (const float*)d_in[3],  *bq1 = (const float*)d_in[4];
    const float* Wk1 = (const float*)d_in[5],  *bk1 = (const float*)d_in[6];
    const float* Wv1 = (const float*)d_in[7],  *bv1 = (const float*)d_in[8];
    const float* Ws1 = (const float*)d_in[9],  *bs1 = (const float*)d_in[10];
    const float* Wq2 = (const float*)d_in[11], *bq2 = (const float*)d_in[12];
    const float* Wk2 = (const float*)d_in[13], *bk2 = (const float*)d_in[14];
    const float* Wv2 = (const float*)d_in[15], *bv2 = (const float*)d_in[16];
    const float* Ws2 = (const float*)d_in[17], *bs2 = (const float*)d_in[18];
    const float* Wfc = (const float*)d_in[19], *bfc = (const float*)d_in[20];

    int N = in_sizes[0] / 128;
    int E = in_sizes[1] / 2;
    int rdiv = (N + NR - 1) / NR;            // 391 nodes per range
    float rinv = 1.0f / (float)rdiv;
    int NB = (E + EPB - 1) / EPB;            // scatter blocks

    // ---- workspace layout ----
    float* ws = (float*)d_ws;
    float* qs1    = ws;                                   // N*64 f  (q|s conv1)
    float* h1     = qs1 + (size_t)N * 64;                 // N*32 f  (aliased rsrc)
    float* h2     = h1 + (size_t)N * 32;                  // N*16 f  (aliased rdst lo)
    float* qs2    = h2 + (size_t)N * 16;                  // N*32 f  (rdst overflow)
    float* pooled = qs2 + (size_t)N * 32;                 // 1024 f
    float* cnt    = pooled + 1024;                        // 64 f
    unsigned char* kv1 = (unsigned char*)(cnt + 64);      // N*64 fp8 head-interleaved
    unsigned char* kv2 = kv1 + (size_t)N * 64;            // N*32 fp8 head-interleaved
    int* deg     = (int*)(kv2 + (size_t)N * 32);          // N
    int* row_ptr = deg + N;                               // N+1 (sentinel)
    int* rstart  = row_ptr + N + 1;                       // NR+1
    int* qtot    = rstart + NR + 1;                       // NR (reused as dsort tot)
    int* col     = qtot + NR;                             // E
    int* order   = col + E;                               // N
    int* pcnt    = order + N;                             // NB*NR
    int* phd     = pcnt + (size_t)NB * NR;                // NR*256
    unsigned short* wp1 = (unsigned short*)(phd + (size_t)NR * 256); // 16384 bf16
    unsigned short* wp2 = wp1 + 16384;                    // 2048 bf16
    int* rsrc = (int*)h1;                                 // E ints (N*32 == E)
    int* rdst = (int*)h2;                                 // E ints (spills into qs2)

    // zero: pooled + cnt accumulators only (everything else fully written)
    hipMemsetAsync(pooled, 0, (1024 + 64) * sizeof(float), stream);

    int ngrid = (N * HEADS + 255) / 256;
    int mtiles = (N + 63) / 64;

    // ---- weight packing (independent, tiny) ----
    pack_w1<<<8, 256, 0, stream>>>(Wq1, Wk1, Wv1, Ws1, wp1);
    pack_w2<<<1, 256, 0, stream>>>(Wq2, Wk2, Wv2, Ws2, wp2);

    // ---- CSR build + fused degree sort (LDS atomics only) ----
    scatter_count<<<NB, 256, 0, stream>>>(ei, E, rdiv, rinv, pcnt);
    qprefix<<<NR, 256, 0, stream>>>(pcnt, NB, qtot);
    qscan<<<1, NR, 0, stream>>>(qtot, rstart);
    scatter_place<<<NB, 256, 0, stream>>>(ei, E, rdiv, rinv, pcnt, rstart, rsrc, rdst);
    deg_range_place<<<NR, 256, 0, stream>>>(rsrc, rdst, rstart, deg, row_ptr, phd, col, N, rdiv, E);
    dsort_scanA<<<NR, 256, 0, stream>>>(phd, qtot);
    dsort_scanB<<<1, 256, 0, stream>>>(qtot);
    dsort_place<<<NR, 256, 0, stream>>>(phd, qtot, deg, order, N, rdiv);

    // ---- conv1 ----
    proj1_mfma<<<mtiles, 256, 0, stream>>>(x, wp1, bq1, bk1, bv1, bs1, qs1, kv1, N);
    gather_conv1<<<ngrid, 256, 0, stream>>>(row_ptr, order, col, qs1, kv1, h1, N);

    // ---- conv2 ----
    proj2_mfma<<<mtiles, 256, 0, stream>>>(h1, wp2, bq2, bk2, bv2, bs2, qs2, kv2, N);
    gather_conv2<<<ngrid, 256, 0, stream>>>(row_ptr, order, col, qs2, kv2, h2, N);

    // ---- pool + fc ----
    pool_kernel<<<(N + 15) / 16, 256, 0, stream>>>(h2, batch, pooled, cnt, N);
    fc_kernel<<<1, 640, 0, stream>>>(pooled, cnt, Wfc, bfc, (float*)d_out);
}